// Round 1
// baseline (7065.550 us; speedup 1.0000x reference)
//
#include <hip/hip_runtime.h>

#define N_NODES 100000
#define N_EDGES 1600000

// ---------------- init: out[n,o] = bias[o] + sum_f h[n,f]*root[f,o] ----------------
template<int Fin, int Fout>
__global__ __launch_bounds__(256) void init_out_k(const float* __restrict__ h,
                                                  const float* __restrict__ root,
                                                  const float* __restrict__ bias,
                                                  float* __restrict__ out) {
    int n = blockIdx.x * 256 + threadIdx.x;
    if (n >= N_NODES) return;
    float xr[Fin];
    if constexpr (Fin % 4 == 0) {
        const float4* xv = reinterpret_cast<const float4*>(h + (size_t)n * Fin);
        #pragma unroll
        for (int f = 0; f < Fin / 4; ++f) {
            float4 t = xv[f];
            xr[4*f+0] = t.x; xr[4*f+1] = t.y; xr[4*f+2] = t.z; xr[4*f+3] = t.w;
        }
    } else {
        #pragma unroll
        for (int f = 0; f < Fin; ++f) xr[f] = h[(size_t)n * Fin + f];
    }
    float z[Fout];
    #pragma unroll
    for (int o = 0; o < Fout; ++o) z[o] = bias[o];
    #pragma unroll
    for (int f = 0; f < Fin; ++f) {
        #pragma unroll
        for (int o = 0; o < Fout; ++o) z[o] += xr[f] * root[f * Fout + o];
    }
    #pragma unroll
    for (int o = 0; o < Fout; ++o) out[(size_t)n * Fout + o] = z[o];
}

// ---------------- edge pass: out[dst] += sum_b w_b * (x[src] @ W[idx_b]) ----------------
template<int Fin, int Fout>
__global__ __launch_bounds__(256) void edge_k(const float* __restrict__ h,
                                              const int* __restrict__ src,
                                              const int* __restrict__ dst,
                                              const float* __restrict__ pseudo,
                                              const float* __restrict__ W,
                                              float* __restrict__ out) {
    constexpr int KFF = Fin * Fout;
    constexpr int STRIDE = KFF + 1;          // odd stride -> bank = idx (mod 32), conflict-light
    __shared__ float sW[27 * STRIDE];
    for (int i = threadIdx.x; i < 27 * KFF; i += 256) {
        int k = i / KFF;
        int r = i - k * KFF;
        sW[k * STRIDE + r] = W[i];
    }
    __syncthreads();

    int e = blockIdx.x * 256 + threadIdx.x;
    if (e >= N_EDGES) return;

    int s = src[e];
    int d = dst[e];

    size_t pb = (size_t)e * 3;
    float v0 = pseudo[pb + 0] * 2.0f;
    float v1 = pseudo[pb + 1] * 2.0f;
    float v2 = pseudo[pb + 2] * 2.0f;
    float f0 = fmaxf(fminf(floorf(v0), 1.0f), 0.0f);
    float f1 = fmaxf(fminf(floorf(v1), 1.0f), 0.0f);
    float f2 = fmaxf(fminf(floorf(v2), 1.0f), 0.0f);
    float fr0 = v0 - f0, fr1 = v1 - f1, fr2 = v2 - f2;
    int i0 = (int)f0, i1 = (int)f1, i2 = (int)f2;
    float w0[2] = {1.0f - fr0, fr0};
    float w1[2] = {1.0f - fr1, fr1};
    float w2[2] = {1.0f - fr2, fr2};

    float xr[Fin];
    if constexpr (Fin % 4 == 0) {
        const float4* xv = reinterpret_cast<const float4*>(h + (size_t)s * Fin);
        #pragma unroll
        for (int f = 0; f < Fin / 4; ++f) {
            float4 t = xv[f];
            xr[4*f+0] = t.x; xr[4*f+1] = t.y; xr[4*f+2] = t.z; xr[4*f+3] = t.w;
        }
    } else {
        #pragma unroll
        for (int f = 0; f < Fin; ++f) xr[f] = h[(size_t)s * Fin + f];
    }

    float z[Fout];
    #pragma unroll
    for (int o = 0; o < Fout; ++o) z[o] = 0.0f;

    #pragma unroll
    for (int b = 0; b < 8; ++b) {
        const int b0 = b & 1, b1 = (b >> 1) & 1, b2 = (b >> 2) & 1;
        float wb = w0[b0] * w1[b1] * w2[b2];
        int idx = (i0 + b0) + 3 * (i1 + b1) + 9 * (i2 + b2);
        const float* wp = &sW[idx * STRIDE];
        #pragma unroll
        for (int f = 0; f < Fin; ++f) {
            float a = wb * xr[f];
            #pragma unroll
            for (int o = 0; o < Fout; ++o) z[o] += a * wp[f * Fout + o];
        }
    }

    float* op = out + (size_t)d * Fout;
    #pragma unroll
    for (int o = 0; o < Fout; ++o) atomicAdd(&op[o], z[o]);
}

// ---------------- elementwise ELU ----------------
__global__ __launch_bounds__(256) void elu_k(float* __restrict__ p, int total) {
    int i = blockIdx.x * 256 + threadIdx.x;
    if (i < total) {
        float t = p[i];
        p[i] = t > 0.0f ? t : (expf(t) - 1.0f);
    }
}

template<int Fin, int Fout>
static void run_layer(const float* hin, float* hout,
                      const float* W, const float* root, const float* bias,
                      const int* src, const int* dst, const float* pseudo,
                      hipStream_t stream) {
    init_out_k<Fin, Fout><<<(N_NODES + 255) / 256, 256, 0, stream>>>(hin, root, bias, hout);
    edge_k<Fin, Fout><<<(N_EDGES + 255) / 256, 256, 0, stream>>>(hin, src, dst, pseudo, W, hout);
    int total = N_NODES * Fout;
    elu_k<<<(total + 255) / 256, 256, 0, stream>>>(hout, total);
}

extern "C" void kernel_launch(void* const* d_in, const int* in_sizes, int n_in,
                              void* d_out, int out_size, void* d_ws, size_t ws_size,
                              hipStream_t stream) {
    const float* x      = (const float*)d_in[0];
    const int*   ei     = (const int*)d_in[1];
    const float* pseudo = (const float*)d_in[2];
    const int* src = ei;
    const int* dst = ei + N_EDGES;

    const float* W[6]; const float* R[6]; const float* B[6];
    for (int i = 0; i < 6; ++i) {
        W[i] = (const float*)d_in[3 + 3 * i];
        R[i] = (const float*)d_in[4 + 3 * i];
        B[i] = (const float*)d_in[5 + 3 * i];
    }

    float* hA = (float*)d_ws;
    float* hB = hA + (size_t)N_NODES * 32;
    float* out = (float*)d_out;

    run_layer<1, 8>  (x,  hA, W[0], R[0], B[0], src, dst, pseudo, stream);
    run_layer<8, 16> (hA, hB, W[1], R[1], B[1], src, dst, pseudo, stream);
    run_layer<16, 32>(hB, hA, W[2], R[2], B[2], src, dst, pseudo, stream);
    run_layer<32, 16>(hA, hB, W[3], R[3], B[3], src, dst, pseudo, stream);
    run_layer<16, 8> (hB, hA, W[4], R[4], B[4], src, dst, pseudo, stream);
    run_layer<8, 1>  (hA, out, W[5], R[5], B[5], src, dst, pseudo, stream);
}